// Round 6
// baseline (216.396 us; speedup 1.0000x reference)
//
#include <hip/hip_runtime.h>
#include <hip/hip_bf16.h>
#include <cstdint>
#include <cstddef>

#define Bn 8192
#define Dn 512
#define Sn 16

typedef __attribute__((ext_vector_type(4))) float f32x4;
typedef __attribute__((ext_vector_type(8))) __bf16 bf16x8;
typedef __attribute__((ext_vector_type(8))) short short8;

union BF8 { short8 s; __hip_bfloat16 h[8]; };

__device__ __forceinline__ void gload16(const void* gsrc, void* ldst){
  __builtin_amdgcn_global_load_lds(
      (const __attribute__((address_space(1))) void*)gsrc,
      (__attribute__((address_space(3))) void*)ldst, 16, 0, 0);
}
__device__ __forceinline__ float bf2f(unsigned short u){
  union { unsigned int i; float f; } c; c.i = ((unsigned int)u) << 16; return c.f;
}

// ---------- fused prep (weight cast, A=-exp) + LayerNorm ----------
__global__ __launch_bounds__(256) void prep_ln_kernel(
    const float* __restrict__ w1, const float* __restrict__ v1,
    const float* __restrict__ dt, const float* __restrict__ w2,
    const float* __restrict__ Bp, const float* __restrict__ Cp,
    const float* __restrict__ Alog,
    const float* __restrict__ x, const float* __restrict__ g,
    const float* __restrict__ bta,
    __hip_bfloat16* __restrict__ w1b, __hip_bfloat16* __restrict__ v1b,
    __hip_bfloat16* __restrict__ dtb, __hip_bfloat16* __restrict__ w2b,
    __hip_bfloat16* __restrict__ bpcpb, float* __restrict__ A,
    __hip_bfloat16* __restrict__ xn)
{
  const int bid = blockIdx.x;
  if(bid < Dn*Dn/256){
    const int i = bid*256 + threadIdx.x;
    w1b[i] = __float2bfloat16(w1[i]);
    v1b[i] = __float2bfloat16(v1[i]);
    dtb[i] = __float2bfloat16(dt[i]);
    w2b[i] = __float2bfloat16(w2[i]);
    if(i < Sn*Dn){
      bpcpb[i]         = __float2bfloat16(Bp[i]);
      bpcpb[Sn*Dn + i] = __float2bfloat16(Cp[i]);
      A[i] = -expf(Alog[i]);
    }
  } else {
    const int lane = threadIdx.x & 63;
    const int row  = (bid - Dn*Dn/256)*4 + (threadIdx.x >> 6);
    const float* xr = x + (size_t)row*Dn;
    const int c = lane*8;
    f32x4 a0 = *(const f32x4*)(xr + c);
    f32x4 a1 = *(const f32x4*)(xr + c + 4);
    float s = 0.f, q = 0.f;
    #pragma unroll
    for(int j=0;j<4;j++){ s += a0[j]+a1[j]; q += a0[j]*a0[j] + a1[j]*a1[j]; }
    #pragma unroll
    for(int off=32; off; off >>= 1){ s += __shfl_xor(s, off); q += __shfl_xor(q, off); }
    const float mu = s * (1.f/Dn);
    const float rs = rsqrtf(q*(1.f/Dn) - mu*mu + 1e-5f);
    f32x4 g0 = *(const f32x4*)(g + c);
    f32x4 g1 = *(const f32x4*)(g + c + 4);
    f32x4 b0 = *(const f32x4*)(bta + c);
    f32x4 b1 = *(const f32x4*)(bta + c + 4);
    BF8 o;
    #pragma unroll
    for(int j=0;j<4;j++){
      o.h[j]   = __float2bfloat16((a0[j]-mu)*rs*g0[j] + b0[j]);
      o.h[4+j] = __float2bfloat16((a1[j]-mu)*rs*g1[j] + b1[j]);
    }
    *(short8*)(xn + (size_t)row*Dn + c) = o.s;
  }
}

// ---------- tiled MFMA GEMM, 3-buffer distance-2 pipeline (race-free) ----------
// C[M,N] = act(X[M,K] @ W[N,K]^T + bias);  DUAL: W2 shares the A-tile.
// Tile BM=128, BN=64, BK=32, 256 threads.  Swizzle: chunk ^= (row+(row>>3))&3.
// Sync protocol: a barrier releases tile t+1 only AFTER every wave has drained
// its own tile-(t+1) loads (vmcnt(L) with only tile t+2 left in flight).
// Per iter t: stage(t+2) ; ds_read(t) ; MFMA(t) ; vmcnt(L) ; s_barrier.
// Prologue: stage(0); stage(1); vmcnt(L); barrier  -> tile 0 visible to ALL waves.
template<int ACT1, int ACT2, bool DUAL, bool OBF>
__global__ __launch_bounds__(256) void tgemm_kernel(
    const __hip_bfloat16* __restrict__ X,
    const __hip_bfloat16* __restrict__ W1,
    const __hip_bfloat16* __restrict__ W2,
    const float* __restrict__ bias1,
    const float* __restrict__ bias2,
    const float* __restrict__ convw,
    void* __restrict__ out1, void* __restrict__ out2,
    int M, int N, int K)
{
  constexpr int AB    = 8192;                 // 128 x 32 bf16
  constexpr int B1B   = 4096;                 // 64 x 32 bf16
  constexpr int BUFSZ = AB + B1B + (DUAL ? 4096 : 0);
  __shared__ char smem[3*BUFSZ] __attribute__((aligned(128)));

  const int tid  = threadIdx.x;
  const int wv   = tid >> 6;
  const int lane = tid & 63;

  // XCD-aware bijective remap (grid = 512, %8 == 0)
  const int r    = blockIdx.x + blockIdx.y*gridDim.x;
  const int qq   = (gridDim.x*gridDim.y) >> 3;
  const int o    = (r & 7)*qq + (r >> 3);
  const int tx   = o % gridDim.x;
  const int ty   = o / gridDim.x;
  const int r0 = ty * 128;
  const int c0 = tx * 64;

  f32x4 acc1[4][2] = {};
  f32x4 acc2[4][2] = {};

  const int lr = lane & 15;
  const int lg = lane >> 4;

  auto stage = [&](int buf, int kk){
    char* base = smem + buf*BUFSZ;
    #pragma unroll
    for(int i=0;i<2;i++){
      const int off = i*4096 + tid*16;
      const int row = off >> 6;
      const int g   = ((off>>4)&3) ^ ((row + (row>>3)) & 3);
      gload16(X + (size_t)(r0+row)*K + kk + g*8, base + i*4096 + (wv<<10));
    }
    {
      const int off = tid*16;
      const int row = off >> 6;
      const int g   = ((off>>4)&3) ^ ((row + (row>>3)) & 3);
      gload16(W1 + (size_t)(c0+row)*K + kk + g*8, base + AB + (wv<<10));
      if(DUAL)
        gload16(W2 + (size_t)(c0+row)*K + kk + g*8, base + AB + B1B + (wv<<10));
    }
  };

  const int NT = K >> 5;
  stage(0, 0);
  stage(1, 32);
  if constexpr (DUAL) asm volatile("s_waitcnt vmcnt(4)" ::: "memory");
  else                asm volatile("s_waitcnt vmcnt(3)" ::: "memory");
  __builtin_amdgcn_s_barrier();

  int cur = 0;
  for(int t=0; t<NT; ++t){
    if(t+2 < NT){
      int nb = cur + 2; if(nb >= 3) nb -= 3;
      stage(nb, (t+2)<<5);      // overwrites buf (t-1)%3: reads done at barrier(t-1)
    }

    const char* base = smem + cur*BUFSZ;
    bf16x8 af[4], b1f[2], b2f[2];
    #pragma unroll
    for(int m=0;m<4;m++){
      const int rr = (wv>>1)*64 + m*16 + lr;
      const int cc = lg ^ ((rr + (rr>>3)) & 3);
      af[m] = *(const bf16x8*)(base + rr*64 + cc*16);
    }
    #pragma unroll
    for(int n=0;n<2;n++){
      const int rr = (wv&1)*32 + n*16 + lr;
      const int cc = lg ^ ((rr + (rr>>3)) & 3);
      b1f[n] = *(const bf16x8*)(base + AB + rr*64 + cc*16);
      if(DUAL)
        b2f[n] = *(const bf16x8*)(base + AB + B1B + rr*64 + cc*16);
    }

    #pragma unroll
    for(int m=0;m<4;m++){
      #pragma unroll
      for(int n=0;n<2;n++){
        acc1[m][n] = __builtin_amdgcn_mfma_f32_16x16x32_bf16(af[m], b1f[n], acc1[m][n], 0, 0, 0);
        if(DUAL)
          acc2[m][n] = __builtin_amdgcn_mfma_f32_16x16x32_bf16(af[m], b2f[n], acc2[m][n], 0, 0, 0);
      }
    }

    if(t+1 < NT){
      if(t+2 < NT){
        // outstanding: tile t+1 (L) + tile t+2 (L); drain tile t+1 before barrier
        if constexpr (DUAL) asm volatile("s_waitcnt vmcnt(4)" ::: "memory");
        else                asm volatile("s_waitcnt vmcnt(3)" ::: "memory");
      } else {
        asm volatile("s_waitcnt vmcnt(0)" ::: "memory");
      }
      __builtin_amdgcn_s_barrier();   // releases tile t+1 for ALL waves
    }
    cur += 1; if(cur == 3) cur = 0;
  }

  const int er = lg*4;
  const int ec = lr;
  #pragma unroll
  for(int n=0;n<2;n++){
    const int cc = c0 + (wv&1)*32 + n*16 + ec;
    const float bv1 = bias1[cc];
    const float cwv = (ACT1==1) ? convw[cc*3+1] : 0.f;
    const float bv2 = DUAL ? bias2[cc] : 0.f;
    #pragma unroll
    for(int m=0;m<4;m++){
      #pragma unroll
      for(int j=0;j<4;j++){
        const int rr = r0 + (wv>>1)*64 + m*16 + er + j;
        float y = acc1[m][n][j] + bv1;
        if(ACT1==1){ float z = y*cwv; y = z/(1.f + __expf(-z)); }
        if(ACT1==2){ y = y/(1.f + __expf(-y)); }
        if(ACT1==3){ y = (y > 20.f) ? y : log1pf(__expf(y)); }
        if(OBF) ((__hip_bfloat16*)out1)[(size_t)rr*N + cc] = __float2bfloat16(y);
        else    ((float*)out1)[(size_t)rr*N + cc] = y;
        if(DUAL){
          float y2 = acc2[m][n][j] + bv2;
          if(ACT2==1){ float z = y2*cwv; y2 = z/(1.f + __expf(-z)); }
          if(ACT2==2){ y2 = y2/(1.f + __expf(-y2)); }
          if(ACT2==3){ y2 = (y2 > 20.f) ? y2 : log1pf(__expf(y2)); }
          if(OBF) ((__hip_bfloat16*)out2)[(size_t)rr*N + cc] = __float2bfloat16(y2);
          else    ((float*)out2)[(size_t)rr*N + cc] = y2;
        }
      }
    }
  }
}

// ---------- SSM elementwise + in-block Bm/Cm projection ----------
__global__ __launch_bounds__(256) void ssm_kernel(
    const float* __restrict__ state,
    const __hip_bfloat16* __restrict__ delta,
    const __hip_bfloat16* __restrict__ xconv,
    const __hip_bfloat16* __restrict__ vbuf,
    const __hip_bfloat16* __restrict__ W3,     // [32][512] = Bp;Cp rows
    const float* __restrict__ bpb, const float* __restrict__ cpb,
    const float* __restrict__ A,
    float* __restrict__ nstate,
    __hip_bfloat16* __restrict__ gbuf)
{
  const int b = blockIdx.x;
  const int tid = threadIdx.x;
  __shared__ float xcs[512];
  __shared__ float dls[512];
  __shared__ float red[256];
  __shared__ float sBC[32];

  {
    const unsigned int vx = *(const unsigned int*)(xconv + (size_t)b*Dn + tid*2);
    const unsigned int vd = *(const unsigned int*)(delta + (size_t)b*Dn + tid*2);
    xcs[tid*2]   = bf2f((unsigned short)(vx & 0xffff));
    xcs[tid*2+1] = bf2f((unsigned short)(vx >> 16));
    dls[tid*2]   = bf2f((unsigned short)(vd & 0xffff));
    dls[tid*2+1] = bf2f((unsigned short)(vd >> 16));
  }
  __syncthreads();
  {
    const int n  = tid & 31;
    const int ch = tid >> 5;
    const __hip_bfloat16* wr = W3 + (size_t)n*Dn + ch*64;
    float p = 0.f;
    #pragma unroll
    for(int j=0;j<64;j+=8){
      bf16x8 w = *(const bf16x8*)(wr + j);
      #pragma unroll
      for(int e=0;e<8;e++) p += xcs[ch*64 + j + e] * (float)w[e];
    }
    red[tid] = p;
  }
  __syncthreads();
  if(tid < 32){
    float s = (tid < 16) ? bpb[tid] : cpb[tid-16];
    #pragma unroll
    for(int c2=0;c2<8;c2++) s += red[tid + 32*c2];
    sBC[tid] = s;
  }
  __syncthreads();

  const int qlane = tid & 3;
  #pragma unroll
  for(int it=0; it<8; ++it){
    const int d = it*64 + (tid >> 2);
    const float dl = dls[d];
    const float xc = xcs[d];
    const size_t off = ((size_t)b*Dn + d)*Sn + qlane*4;
    f32x4 st = *(const f32x4*)(state + off);
    f32x4 Av = *(const f32x4*)(A + d*Sn + qlane*4);
    f32x4 ns;
    float xs = 0.f;
    #pragma unroll
    for(int j=0;j<4;j++){
      const int s = qlane*4 + j;
      const float da = __expf(dl * Av[j]);
      const float nv = st[j]*da + dl*sBC[s]*xc;
      ns[j] = nv;
      xs += nv * sBC[16+s];
    }
    *(f32x4*)(nstate + off) = ns;
    xs += __shfl_xor(xs, 1);
    xs += __shfl_xor(xs, 2);
    if(qlane == 0){
      const float vv = __bfloat162float(vbuf[(size_t)b*Dn + d]);
      gbuf[(size_t)b*Dn + d] = __float2bfloat16(xs * vv);
    }
  }
}

extern "C" void kernel_launch(void* const* d_in, const int* in_sizes, int n_in,
                              void* d_out, int out_size, void* d_ws, size_t ws_size,
                              hipStream_t stream)
{
  const float* x      = (const float*)d_in[0];
  const float* sst    = (const float*)d_in[1];
  const float* ln_g   = (const float*)d_in[2];
  const float* ln_b   = (const float*)d_in[3];
  const float* w1_W   = (const float*)d_in[4];
  const float* w1_b   = (const float*)d_in[5];
  const float* v1_W   = (const float*)d_in[6];
  const float* v1_b   = (const float*)d_in[7];
  const float* w2_W   = (const float*)d_in[8];
  const float* w2_b   = (const float*)d_in[9];
  const float* conv_w = (const float*)d_in[10];
  const float* A_log  = (const float*)d_in[11];
  const float* Bp_W   = (const float*)d_in[12];
  const float* Bp_b   = (const float*)d_in[13];
  const float* Cp_W   = (const float*)d_in[14];
  const float* Cp_b   = (const float*)d_in[15];
  const float* dt_W   = (const float*)d_in[16];
  const float* dt_b   = (const float*)d_in[17];

  float* out    = (float*)d_out;
  float* nstate = out + (size_t)Bn*Dn;

  char* wsp = (char*)d_ws;
  auto alloc = [&](size_t bytes)->char*{
    char* p = wsp; wsp += (bytes + 255) & ~(size_t)255; return p;
  };
  __hip_bfloat16* xnorm = (__hip_bfloat16*)alloc((size_t)Bn*Dn*2);
  __hip_bfloat16* xconv = (__hip_bfloat16*)alloc((size_t)Bn*Dn*2);
  __hip_bfloat16* vbuf  = (__hip_bfloat16*)alloc((size_t)Bn*Dn*2);
  __hip_bfloat16* gbuf  = (__hip_bfloat16*)alloc((size_t)Bn*Dn*2);
  __hip_bfloat16* delta = (__hip_bfloat16*)alloc((size_t)Bn*Dn*2);
  __hip_bfloat16* w1b   = (__hip_bfloat16*)alloc((size_t)Dn*Dn*2);
  __hip_bfloat16* v1b   = (__hip_bfloat16*)alloc((size_t)Dn*Dn*2);
  __hip_bfloat16* dtb   = (__hip_bfloat16*)alloc((size_t)Dn*Dn*2);
  __hip_bfloat16* w2b   = (__hip_bfloat16*)alloc((size_t)Dn*Dn*2);
  __hip_bfloat16* bpcpb = (__hip_bfloat16*)alloc((size_t)2*Sn*Dn*2);
  float*          Abuf  = (float*)alloc((size_t)Dn*Sn*4);

  // 1. prep + layernorm (fused, independent halves)
  prep_ln_kernel<<<dim3(Dn*Dn/256 + Bn/4), dim3(256), 0, stream>>>(
      w1_W, v1_W, dt_W, w2_W, Bp_W, Cp_W, A_log, x, ln_g, ln_b,
      w1b, v1b, dtb, w2b, bpcpb, Abuf, xnorm);
  // 2. fused: x_conv = silu((x_norm@w1^T + b)*cw), v = silu(x_norm@v1^T + b)
  tgemm_kernel<1,2,true,true><<<dim3(Dn/64, Bn/128), dim3(256), 0, stream>>>(
      xnorm, w1b, v1b, w1_b, v1_b, conv_w, (void*)xconv, (void*)vbuf, Bn, Dn, Dn);
  // 3. delta = softplus(x_conv@dt^T + b) (bf16)
  tgemm_kernel<3,0,false,true><<<dim3(Dn/64, Bn/128), dim3(256), 0, stream>>>(
      xconv, dtb, nullptr, dt_b, nullptr, nullptr, (void*)delta, nullptr, Bn, Dn, Dn);
  // 4. SSM elementwise + Bm/Cm + g
  ssm_kernel<<<dim3(Bn), dim3(256), 0, stream>>>(
      sst, delta, xconv, vbuf, bpcpb, Bp_b, Cp_b, Abuf, nstate, gbuf);
  // 5. out = g@w2^T + b (fp32)
  tgemm_kernel<0,0,false,false><<<dim3(Dn/64, Bn/128), dim3(256), 0, stream>>>(
      gbuf, w2b, nullptr, w2_b, nullptr, nullptr, (void*)out, nullptr, Bn, Dn, Dn);
}

// Round 7
// 200.664 us; speedup vs baseline: 1.0784x; 1.0784x over previous
//
#include <hip/hip_runtime.h>
#include <hip/hip_bf16.h>
#include <cstdint>
#include <cstddef>

#define Bn 8192
#define Dn 512
#define Sn 16

typedef __attribute__((ext_vector_type(4))) float f32x4;
typedef __attribute__((ext_vector_type(8))) __bf16 bf16x8;
typedef __attribute__((ext_vector_type(8))) short short8;

union BF8 { short8 s; __hip_bfloat16 h[8]; };

__device__ __forceinline__ void gload16(const void* gsrc, void* ldst){
  __builtin_amdgcn_global_load_lds(
      (const __attribute__((address_space(1))) void*)gsrc,
      (__attribute__((address_space(3))) void*)ldst, 16, 0, 0);
}
__device__ __forceinline__ float bf2f(unsigned short u){
  union { unsigned int i; float f; } c; c.i = ((unsigned int)u) << 16; return c.f;
}

// ---------- fused prep (weight cast, A=-exp) + LayerNorm ----------
__global__ __launch_bounds__(256) void prep_ln_kernel(
    const float* __restrict__ w1, const float* __restrict__ v1,
    const float* __restrict__ dt, const float* __restrict__ w2,
    const float* __restrict__ Bp, const float* __restrict__ Cp,
    const float* __restrict__ Alog,
    const float* __restrict__ x, const float* __restrict__ g,
    const float* __restrict__ bta,
    __hip_bfloat16* __restrict__ w1b, __hip_bfloat16* __restrict__ v1b,
    __hip_bfloat16* __restrict__ dtb, __hip_bfloat16* __restrict__ w2b,
    __hip_bfloat16* __restrict__ bpcpb, float* __restrict__ A,
    __hip_bfloat16* __restrict__ xn)
{
  const int bid = blockIdx.x;
  if(bid < Dn*Dn/256){
    const int i = bid*256 + threadIdx.x;
    w1b[i] = __float2bfloat16(w1[i]);
    v1b[i] = __float2bfloat16(v1[i]);
    dtb[i] = __float2bfloat16(dt[i]);
    w2b[i] = __float2bfloat16(w2[i]);
    if(i < Sn*Dn){
      bpcpb[i]         = __float2bfloat16(Bp[i]);
      bpcpb[Sn*Dn + i] = __float2bfloat16(Cp[i]);
      A[i] = -expf(Alog[i]);
    }
  } else {
    const int lane = threadIdx.x & 63;
    const int row  = (bid - Dn*Dn/256)*4 + (threadIdx.x >> 6);
    const float* xr = x + (size_t)row*Dn;
    const int c = lane*8;
    f32x4 a0 = *(const f32x4*)(xr + c);
    f32x4 a1 = *(const f32x4*)(xr + c + 4);
    float s = 0.f, q = 0.f;
    #pragma unroll
    for(int j=0;j<4;j++){ s += a0[j]+a1[j]; q += a0[j]*a0[j] + a1[j]*a1[j]; }
    #pragma unroll
    for(int off=32; off; off >>= 1){ s += __shfl_xor(s, off); q += __shfl_xor(q, off); }
    const float mu = s * (1.f/Dn);
    const float rs = rsqrtf(q*(1.f/Dn) - mu*mu + 1e-5f);
    f32x4 g0 = *(const f32x4*)(g + c);
    f32x4 g1 = *(const f32x4*)(g + c + 4);
    f32x4 b0 = *(const f32x4*)(bta + c);
    f32x4 b1 = *(const f32x4*)(bta + c + 4);
    BF8 o;
    #pragma unroll
    for(int j=0;j<4;j++){
      o.h[j]   = __float2bfloat16((a0[j]-mu)*rs*g0[j] + b0[j]);
      o.h[4+j] = __float2bfloat16((a1[j]-mu)*rs*g1[j] + b1[j]);
    }
    *(short8*)(xn + (size_t)row*Dn + c) = o.s;
  }
}

// ---------- tiled MFMA GEMM, 3-buffer distance-2 pipeline (race-free) ----------
// Identical protocol to round 6 (verified): per iter t:
//   stage(t+2) ; ds_read(t) ; MFMA(t) ; vmcnt(L) [drains t+1] ; s_barrier.
template<int ACT1, int ACT2, bool DUAL, bool OBF>
__global__ __launch_bounds__(256) void tgemm_kernel(
    const __hip_bfloat16* __restrict__ X,
    const __hip_bfloat16* __restrict__ W1,
    const __hip_bfloat16* __restrict__ W2,
    const float* __restrict__ bias1,
    const float* __restrict__ bias2,
    const float* __restrict__ convw,
    void* __restrict__ out1, void* __restrict__ out2,
    int M, int N, int K)
{
  constexpr int AB    = 8192;                 // 128 x 32 bf16
  constexpr int B1B   = 4096;                 // 64 x 32 bf16
  constexpr int BUFSZ = AB + B1B + (DUAL ? 4096 : 0);
  __shared__ char smem[3*BUFSZ] __attribute__((aligned(128)));

  const int tid  = threadIdx.x;
  const int wv   = tid >> 6;
  const int lane = tid & 63;

  const int r    = blockIdx.x + blockIdx.y*gridDim.x;
  const int qq   = (gridDim.x*gridDim.y) >> 3;
  const int o    = (r & 7)*qq + (r >> 3);
  const int tx   = o % gridDim.x;
  const int ty   = o / gridDim.x;
  const int r0 = ty * 128;
  const int c0 = tx * 64;

  f32x4 acc1[4][2] = {};
  f32x4 acc2[4][2] = {};

  const int lr = lane & 15;
  const int lg = lane >> 4;

  auto stage = [&](int buf, int kk){
    char* base = smem + buf*BUFSZ;
    #pragma unroll
    for(int i=0;i<2;i++){
      const int off = i*4096 + tid*16;
      const int row = off >> 6;
      const int g   = ((off>>4)&3) ^ ((row + (row>>3)) & 3);
      gload16(X + (size_t)(r0+row)*K + kk + g*8, base + i*4096 + (wv<<10));
    }
    {
      const int off = tid*16;
      const int row = off >> 6;
      const int g   = ((off>>4)&3) ^ ((row + (row>>3)) & 3);
      gload16(W1 + (size_t)(c0+row)*K + kk + g*8, base + AB + (wv<<10));
      if(DUAL)
        gload16(W2 + (size_t)(c0+row)*K + kk + g*8, base + AB + B1B + (wv<<10));
    }
  };

  const int NT = K >> 5;
  stage(0, 0);
  stage(1, 32);
  if constexpr (DUAL) asm volatile("s_waitcnt vmcnt(4)" ::: "memory");
  else                asm volatile("s_waitcnt vmcnt(3)" ::: "memory");
  __builtin_amdgcn_s_barrier();

  int cur = 0;
  for(int t=0; t<NT; ++t){
    if(t+2 < NT){
      int nb = cur + 2; if(nb >= 3) nb -= 3;
      stage(nb, (t+2)<<5);
    }

    const char* base = smem + cur*BUFSZ;
    bf16x8 af[4], b1f[2], b2f[2];
    #pragma unroll
    for(int m=0;m<4;m++){
      const int rr = (wv>>1)*64 + m*16 + lr;
      const int cc = lg ^ ((rr + (rr>>3)) & 3);
      af[m] = *(const bf16x8*)(base + rr*64 + cc*16);
    }
    #pragma unroll
    for(int n=0;n<2;n++){
      const int rr = (wv&1)*32 + n*16 + lr;
      const int cc = lg ^ ((rr + (rr>>3)) & 3);
      b1f[n] = *(const bf16x8*)(base + AB + rr*64 + cc*16);
      if(DUAL)
        b2f[n] = *(const bf16x8*)(base + AB + B1B + rr*64 + cc*16);
    }

    #pragma unroll
    for(int m=0;m<4;m++){
      #pragma unroll
      for(int n=0;n<2;n++){
        acc1[m][n] = __builtin_amdgcn_mfma_f32_16x16x32_bf16(af[m], b1f[n], acc1[m][n], 0, 0, 0);
        if(DUAL)
          acc2[m][n] = __builtin_amdgcn_mfma_f32_16x16x32_bf16(af[m], b2f[n], acc2[m][n], 0, 0, 0);
      }
    }

    if(t+1 < NT){
      if(t+2 < NT){
        if constexpr (DUAL) asm volatile("s_waitcnt vmcnt(4)" ::: "memory");
        else                asm volatile("s_waitcnt vmcnt(3)" ::: "memory");
      } else {
        asm volatile("s_waitcnt vmcnt(0)" ::: "memory");
      }
      __builtin_amdgcn_s_barrier();
    }
    cur += 1; if(cur == 3) cur = 0;
  }

  const int er = lg*4;
  const int ec = lr;
  #pragma unroll
  for(int n=0;n<2;n++){
    const int cc = c0 + (wv&1)*32 + n*16 + ec;
    const float bv1 = bias1[cc];
    const float cwv = (ACT1==1) ? convw[cc*3+1] : 0.f;
    const float bv2 = DUAL ? bias2[cc] : 0.f;
    #pragma unroll
    for(int m=0;m<4;m++){
      #pragma unroll
      for(int j=0;j<4;j++){
        const int rr = r0 + (wv>>1)*64 + m*16 + er + j;
        float y = acc1[m][n][j] + bv1;
        if(ACT1==1){ float z = y*cwv; y = z/(1.f + __expf(-z)); }
        if(ACT1==2){ y = y/(1.f + __expf(-y)); }
        if(ACT1==3){ y = (y > 20.f) ? y : log1pf(__expf(y)); }
        if(OBF) ((__hip_bfloat16*)out1)[(size_t)rr*N + cc] = __float2bfloat16(y);
        else    ((float*)out1)[(size_t)rr*N + cc] = y;
        if(DUAL){
          float y2 = acc2[m][n][j] + bv2;
          if(ACT2==1){ float z = y2*cwv; y2 = z/(1.f + __expf(-z)); }
          if(ACT2==2){ y2 = y2/(1.f + __expf(-y2)); }
          if(ACT2==3){ y2 = (y2 > 20.f) ? y2 : log1pf(__expf(y2)); }
          if(OBF) ((__hip_bfloat16*)out2)[(size_t)rr*N + cc] = __float2bfloat16(y2);
          else    ((float*)out2)[(size_t)rr*N + cc] = y2;
        }
      }
    }
  }
}

// ---------- small projection: Bm/Cm = x_conv @ [Bp;Cp]^T + bias ----------
__global__ __launch_bounds__(256) void bc_kernel(
    const __hip_bfloat16* __restrict__ xc,
    const __hip_bfloat16* __restrict__ bpcpb,
    const float* __restrict__ bpb, const float* __restrict__ cpb,
    float* __restrict__ BmCm)
{
  const int idx = blockIdx.x*256 + threadIdx.x;
  const int b = idx >> 5;
  const int n = idx & 31;
  const __hip_bfloat16* xr = xc + (size_t)b*Dn;
  const __hip_bfloat16* wr = bpcpb + (size_t)n*Dn;
  float s = (n < 16) ? bpb[n] : cpb[n-16];
  for(int k=0;k<Dn;k+=8){
    bf16x8 xv = *(const bf16x8*)(xr+k);
    bf16x8 wv = *(const bf16x8*)(wr+k);
    #pragma unroll
    for(int j=0;j<8;j++) s += (float)xv[j]*(float)wv[j];
  }
  BmCm[idx] = s;
}

// ---------- SSM elementwise (state prefetch, nt-store, LDS row staging) ----
__global__ __launch_bounds__(256) void ssm_kernel(
    const float* __restrict__ state,
    const __hip_bfloat16* __restrict__ delta,
    const __hip_bfloat16* __restrict__ xconv,
    const __hip_bfloat16* __restrict__ vbuf,
    const float* __restrict__ BmCm,
    const float* __restrict__ A,
    float* __restrict__ nstate,
    __hip_bfloat16* __restrict__ gbuf)
{
  const int b = blockIdx.x;
  const int tid = threadIdx.x;
  __shared__ float xcs[512];
  __shared__ float dls[512];
  __shared__ float sBC[32];

  {
    const unsigned int vx = *(const unsigned int*)(xconv + (size_t)b*Dn + tid*2);
    const unsigned int vd = *(const unsigned int*)(delta + (size_t)b*Dn + tid*2);
    xcs[tid*2]   = bf2f((unsigned short)(vx & 0xffff));
    xcs[tid*2+1] = bf2f((unsigned short)(vx >> 16));
    dls[tid*2]   = bf2f((unsigned short)(vd & 0xffff));
    dls[tid*2+1] = bf2f((unsigned short)(vd >> 16));
  }
  if(tid < 32) sBC[tid] = BmCm[(size_t)b*32 + tid];
  __syncthreads();

  const int qlane = tid & 3;
  const int dbase = tid >> 2;
  const size_t rowoff = ((size_t)b*Dn + dbase)*Sn + qlane*4;

  f32x4 st = *(const f32x4*)(state + rowoff);
  f32x4 Av = *(const f32x4*)(A + dbase*Sn + qlane*4);

  #pragma unroll
  for(int it=0; it<8; ++it){
    const int d = it*64 + dbase;
    f32x4 st_n, Av_n;
    if(it < 7){
      st_n = *(const f32x4*)(state + rowoff + (size_t)(it+1)*64*Sn);
      Av_n = *(const f32x4*)(A + (d+64)*Sn + qlane*4);
    }
    const float dl = dls[d];
    const float xc = xcs[d];
    f32x4 ns;
    float xs = 0.f;
    #pragma unroll
    for(int j=0;j<4;j++){
      const int s = qlane*4 + j;
      const float da = __expf(dl * Av[j]);
      const float nv = st[j]*da + dl*sBC[s]*xc;
      ns[j] = nv;
      xs += nv * sBC[16+s];
    }
    __builtin_nontemporal_store(ns, (f32x4*)(nstate + rowoff + (size_t)it*64*Sn));
    xs += __shfl_xor(xs, 1);
    xs += __shfl_xor(xs, 2);
    if(qlane == 0){
      const float vv = __bfloat162float(vbuf[(size_t)b*Dn + d]);
      gbuf[(size_t)b*Dn + d] = __float2bfloat16(xs * vv);
    }
    st = st_n;
    Av = Av_n;
  }
}

extern "C" void kernel_launch(void* const* d_in, const int* in_sizes, int n_in,
                              void* d_out, int out_size, void* d_ws, size_t ws_size,
                              hipStream_t stream)
{
  const float* x      = (const float*)d_in[0];
  const float* sst    = (const float*)d_in[1];
  const float* ln_g   = (const float*)d_in[2];
  const float* ln_b   = (const float*)d_in[3];
  const float* w1_W   = (const float*)d_in[4];
  const float* w1_b   = (const float*)d_in[5];
  const float* v1_W   = (const float*)d_in[6];
  const float* v1_b   = (const float*)d_in[7];
  const float* w2_W   = (const float*)d_in[8];
  const float* w2_b   = (const float*)d_in[9];
  const float* conv_w = (const float*)d_in[10];
  const float* A_log  = (const float*)d_in[11];
  const float* Bp_W   = (const float*)d_in[12];
  const float* Bp_b   = (const float*)d_in[13];
  const float* Cp_W   = (const float*)d_in[14];
  const float* Cp_b   = (const float*)d_in[15];
  const float* dt_W   = (const float*)d_in[16];
  const float* dt_b   = (const float*)d_in[17];

  float* out    = (float*)d_out;
  float* nstate = out + (size_t)Bn*Dn;

  char* wsp = (char*)d_ws;
  auto alloc = [&](size_t bytes)->char*{
    char* p = wsp; wsp += (bytes + 255) & ~(size_t)255; return p;
  };
  __hip_bfloat16* xnorm = (__hip_bfloat16*)alloc((size_t)Bn*Dn*2);
  __hip_bfloat16* xconv = (__hip_bfloat16*)alloc((size_t)Bn*Dn*2);
  __hip_bfloat16* vbuf  = (__hip_bfloat16*)alloc((size_t)Bn*Dn*2);
  __hip_bfloat16* gbuf  = (__hip_bfloat16*)alloc((size_t)Bn*Dn*2);
  __hip_bfloat16* delta = (__hip_bfloat16*)alloc((size_t)Bn*Dn*2);
  __hip_bfloat16* w1b   = (__hip_bfloat16*)alloc((size_t)Dn*Dn*2);
  __hip_bfloat16* v1b   = (__hip_bfloat16*)alloc((size_t)Dn*Dn*2);
  __hip_bfloat16* dtb   = (__hip_bfloat16*)alloc((size_t)Dn*Dn*2);
  __hip_bfloat16* w2b   = (__hip_bfloat16*)alloc((size_t)Dn*Dn*2);
  __hip_bfloat16* bpcpb = (__hip_bfloat16*)alloc((size_t)2*Sn*Dn*2);
  float*          BmCm  = (float*)alloc((size_t)Bn*32*4);
  float*          Abuf  = (float*)alloc((size_t)Dn*Sn*4);

  // 1. prep + layernorm (fused, independent halves)
  prep_ln_kernel<<<dim3(Dn*Dn/256 + Bn/4), dim3(256), 0, stream>>>(
      w1_W, v1_W, dt_W, w2_W, Bp_W, Cp_W, A_log, x, ln_g, ln_b,
      w1b, v1b, dtb, w2b, bpcpb, Abuf, xnorm);
  // 2. fused: x_conv = silu((x_norm@w1^T + b)*cw), v = silu(x_norm@v1^T + b)
  tgemm_kernel<1,2,true,true><<<dim3(Dn/64, Bn/128), dim3(256), 0, stream>>>(
      xnorm, w1b, v1b, w1_b, v1_b, conv_w, (void*)xconv, (void*)vbuf, Bn, Dn, Dn);
  // 3. delta = softplus(x_conv@dt^T + b) (bf16)
  tgemm_kernel<3,0,false,true><<<dim3(Dn/64, Bn/128), dim3(256), 0, stream>>>(
      xconv, dtb, nullptr, dt_b, nullptr, nullptr, (void*)delta, nullptr, Bn, Dn, Dn);
  // 4. Bm/Cm projection (small, L2-hot)
  bc_kernel<<<dim3(Bn*32/256), dim3(256), 0, stream>>>(xconv, bpcpb, Bp_b, Cp_b, BmCm);
  // 5. SSM elementwise + g
  ssm_kernel<<<dim3(Bn), dim3(256), 0, stream>>>(
      sst, delta, xconv, vbuf, BmCm, Abuf, nstate, gbuf);
  // 6. out = g@w2^T + b (fp32)
  tgemm_kernel<0,0,false,false><<<dim3(Dn/64, Bn/128), dim3(256), 0, stream>>>(
      gbuf, w2b, nullptr, w2_b, nullptr, nullptr, (void*)out, nullptr, Bn, Dn, Dn);
}